// Round 1
// baseline (762.821 us; speedup 1.0000x reference)
//
#include <hip/hip_runtime.h>
#include <hip/hip_bf16.h>
#include <stdint.h>

typedef __attribute__((ext_vector_type(8))) short bf16x8;
typedef __attribute__((ext_vector_type(4))) float f32x4;

#define B_ 2
#define T_ 2048
#define C_ 2048
#define H_ 16
#define HD_ 128

__device__ inline ushort f2bf(float f) {
  union { float f; uint32_t u; } v; v.f = f;
  uint32_t u = v.u;
  uint32_t r = (u + 0x7fffu + ((u >> 16) & 1u)) >> 16;
  return (ushort)r;
}
__device__ inline float bf2f(ushort h) {
  union { uint32_t u; float f; } v; v.u = ((uint32_t)h) << 16;
  return v.f;
}

typedef const __attribute__((address_space(1))) void* gas1_t;
typedef __attribute__((address_space(3))) void* las3_t;
__device__ inline void gld_lds16(const void* g, void* l) {
  __builtin_amdgcn_global_load_lds((gas1_t)g, (las3_t)l, 16, 0, 0);
}

// ---------------- fp32 -> bf16 conversion ----------------
__global__ __launch_bounds__(256) void k_f2bf(const float* __restrict__ in,
                                              ushort* __restrict__ out, int n4) {
  int i = blockIdx.x * 256 + threadIdx.x;
  if (i < n4) {
    f32x4 v = *(const f32x4*)(in + (size_t)i * 4);
    ushort4 o;
    o.x = f2bf(v[0]); o.y = f2bf(v[1]); o.z = f2bf(v[2]); o.w = f2bf(v[3]);
    *(ushort4*)(out + (size_t)i * 4) = o;
  }
}

// ---------------- GEMM: C[M,N] = A[M,K] * B[N,K]^T (bf16 in, f32 acc) -----
// 128x128 tile, BK=32, 4 waves (2x2 of 64x64), 16x16x32 bf16 MFMA,
// global_load_lds(16B) staging, double-buffered LDS, 2-barrier/K-step.
template <int OUT_BF16>
__global__ __launch_bounds__(256)
void gemm_bt(const ushort* __restrict__ A, const ushort* __restrict__ Bm,
             void* __restrict__ Cout, int M, int N, int K) {
  __shared__ ushort lA[2][128 * 32];
  __shared__ ushort lB[2][128 * 32];
  const int tid = threadIdx.x;
  const int wid = tid >> 6, lane = tid & 63;
  const int bx = blockIdx.x, by = blockIdx.y;
  const size_t rowA0 = (size_t)by * 128, colB0 = (size_t)bx * 128;
  const int sr = lane >> 2, sc = (lane & 3) * 8;

  const ushort* Abase = A + rowA0 * K + sc;
  const ushort* Bbase = Bm + colB0 * K + sc;

  auto stage = [&](int buf, int kt) {
    const ushort* Ak = Abase + (size_t)kt * 32;
    const ushort* Bk = Bbase + (size_t)kt * 32;
    for (int i = 0; i < 2; i++) {
      int chunk = wid * 2 + i;           // this wave's 1KB chunks
      int row = chunk * 16 + sr;         // 16 rows per chunk, 4 lanes/row
      gld_lds16(Ak + (size_t)row * K, &lA[buf][chunk * 512]);
      gld_lds16(Bk + (size_t)row * K, &lB[buf][chunk * 512]);
    }
  };

  f32x4 acc[4][4];
  const f32x4 zf = {0.f, 0.f, 0.f, 0.f};
  for (int i = 0; i < 4; i++)
    for (int j = 0; j < 4; j++) acc[i][j] = zf;

  const int wr = (wid >> 1) * 64, wc = (wid & 1) * 64;
  const int lr = lane & 15, lk = (lane >> 4) * 8;

  stage(0, 0);
  __syncthreads();
  const int NT = K / 32;
  int buf = 0;
  for (int kt = 0; kt < NT; kt++) {
    if (kt + 1 < NT) stage(buf ^ 1, kt + 1);
    bf16x8 af[4], bfr[4];
    for (int i = 0; i < 4; i++)
      af[i] = *(const bf16x8*)&lA[buf][(wr + i * 16 + lr) * 32 + lk];
    for (int j = 0; j < 4; j++)
      bfr[j] = *(const bf16x8*)&lB[buf][(wc + j * 16 + lr) * 32 + lk];
    for (int i = 0; i < 4; i++)
      for (int j = 0; j < 4; j++)
        acc[i][j] = __builtin_amdgcn_mfma_f32_16x16x32_bf16(af[i], bfr[j],
                                                            acc[i][j], 0, 0, 0);
    __syncthreads();
    buf ^= 1;
  }
  const int lq = (lane >> 4) * 4;
  for (int i = 0; i < 4; i++)
    for (int j = 0; j < 4; j++)
      for (int r = 0; r < 4; r++) {
        size_t row = rowA0 + wr + i * 16 + lq + r;
        size_t col = colB0 + wc + j * 16 + lr;
        float v = acc[i][j][r];
        if (OUT_BF16)
          ((ushort*)Cout)[row * (size_t)N + col] = f2bf(v);
        else
          ((float*)Cout)[row * (size_t)N + col] = v;
      }
}

// ---------------- RoPE + split to (B,H,T,hd), scale Q by 1/sqrt(hd) -------
__global__ __launch_bounds__(256)
void rope_split(const ushort* __restrict__ qkv, const float* __restrict__ cosb,
                const float* __restrict__ sinb, ushort* __restrict__ Qr,
                ushort* __restrict__ Kr, ushort* __restrict__ Vr) {
  const int bt = blockIdx.x;
  const int b = bt >> 11, t = bt & 2047;
  const ushort* base = qkv + (size_t)bt * (3 * C_);
  const int tid = threadIdx.x;
  const float rs = 0.08838834764831845f;  // 1/sqrt(128)
  for (int i = 0; i < 4; i++) {
    int idx = tid + i * 256;  // 0..1023 = (h, pair)
    int h = idx >> 6, p = idx & 63;
    float c = cosb[t * 64 + p], s = sinb[t * 64 + p];
    size_t src = (size_t)h * HD_ + 2 * p;
    size_t dst = (((size_t)(b * H_ + h)) * T_ + t) * HD_ + 2 * p;
    // q (rotated + scaled)
    float x1 = bf2f(base[src]), x2 = bf2f(base[src + 1]);
    Qr[dst] = f2bf((x1 * c - x2 * s) * rs);
    Qr[dst + 1] = f2bf((x1 * s + x2 * c) * rs);
    // k (rotated)
    x1 = bf2f(base[C_ + src]); x2 = bf2f(base[C_ + src + 1]);
    Kr[dst] = f2bf(x1 * c - x2 * s);
    Kr[dst + 1] = f2bf(x1 * s + x2 * c);
    // v (copy)
    Vr[dst] = base[2 * C_ + src];
    Vr[dst + 1] = base[2 * C_ + src + 1];
  }
}

// ---------------- causal flash attention ---------------------------------
// grid (T/64, B*H), 256 threads = 4 waves, each wave owns 16 q rows.
// KV tile = 32 rows. K row-major padded; V transposed in LDS; P via LDS.
__global__ __launch_bounds__(256)
void attn_fwd(const ushort* __restrict__ Qr, const ushort* __restrict__ Kr,
              const ushort* __restrict__ Vr, ushort* __restrict__ Out) {
  __shared__ ushort lK[32][136];    // +16B pad per row
  __shared__ ushort lV[128][40];    // transposed: lV[d][k], +16B pad
  __shared__ ushort lP[4][16][40];  // per-wave P tile
  const int tid = threadIdx.x, wid = tid >> 6, lane = tid & 63;
  const int bh = blockIdx.y;
  const int b = bh >> 4, h = bh & 15;
  const int bx = blockIdx.x;
  const int qbase = bx * 64 + wid * 16;
  const int lr = lane & 15, lk8 = (lane >> 4) * 8;

  const ushort* Qp = Qr + ((size_t)bh * T_ + qbase) * HD_;
  const ushort* Kp = Kr + (size_t)bh * T_ * HD_;
  const ushort* Vp = Vr + (size_t)bh * T_ * HD_;

  bf16x8 qf[4];
  for (int dc = 0; dc < 4; dc++)
    qf[dc] = *(const bf16x8*)(Qp + (size_t)lr * HD_ + dc * 32 + lk8);

  f32x4 o[8];
  const f32x4 zf = {0.f, 0.f, 0.f, 0.f};
  for (int dt = 0; dt < 8; dt++) o[dt] = zf;
  float m[4], l[4];
  for (int r = 0; r < 4; r++) { m[r] = -1e30f; l[r] = 0.f; }

  const int nkt = 2 * bx + 2;  // kv tiles this block needs (causal)
  for (int kt = 0; kt < nkt; kt++) {
    // stage K (row-major) and V (transposed)
    for (int i = 0; i < 2; i++) {
      int chunk = tid + i * 256;            // 512 chunks of 8 elements
      int r = chunk >> 4, c = (chunk & 15) * 8;
      bf16x8 kv = *(const bf16x8*)(Kp + ((size_t)(kt * 32 + r)) * HD_ + c);
      *(bf16x8*)&lK[r][c] = kv;
      bf16x8 vv = *(const bf16x8*)(Vp + ((size_t)(kt * 32 + r)) * HD_ + c);
      for (int j = 0; j < 8; j++) lV[c + j][r] = (ushort)vv[j];
    }
    __syncthreads();
    if (kt * 32 <= qbase + 15) {  // wave participates in this tile
      f32x4 s[2];
      for (int kn = 0; kn < 2; kn++) {
        f32x4 a = zf;
        for (int dc = 0; dc < 4; dc++) {
          bf16x8 kf = *(const bf16x8*)&lK[kn * 16 + lr][dc * 32 + lk8];
          a = __builtin_amdgcn_mfma_f32_16x16x32_bf16(qf[dc], kf, a, 0, 0, 0);
        }
        s[kn] = a;
      }
      // causal mask (C layout: col=lane&15 -> k, row=(lane>>4)*4+r -> q)
      const int qrow = qbase + (lane >> 4) * 4;
      for (int kn = 0; kn < 2; kn++) {
        int kg = kt * 32 + kn * 16 + lr;
        for (int r = 0; r < 4; r++)
          if (kg > qrow + r) s[kn][r] = -1e30f;
      }
      // online softmax (row-reduce across the 16-lane group)
      float al[4];
      for (int r = 0; r < 4; r++) {
        float pm = fmaxf(s[0][r], s[1][r]);
        for (int off = 1; off < 16; off <<= 1)
          pm = fmaxf(pm, __shfl_xor(pm, off, 64));
        float mn = fmaxf(m[r], pm);
        float a = __expf(m[r] - mn);
        float p0 = __expf(s[0][r] - mn);
        float p1 = __expf(s[1][r] - mn);
        s[0][r] = p0; s[1][r] = p1;
        float rsum = p0 + p1;
        for (int off = 1; off < 16; off <<= 1)
          rsum += __shfl_xor(rsum, off, 64);
        l[r] = l[r] * a + rsum;
        m[r] = mn;
        al[r] = a;
      }
      for (int dt = 0; dt < 8; dt++)
        for (int r = 0; r < 4; r++) o[dt][r] *= al[r];
      // P (C layout) -> LDS -> A-frag layout
      for (int kn = 0; kn < 2; kn++)
        for (int r = 0; r < 4; r++)
          lP[wid][(lane >> 4) * 4 + r][kn * 16 + lr] = f2bf(s[kn][r]);
      bf16x8 pf = *(const bf16x8*)&lP[wid][lr][lk8];
      for (int dt = 0; dt < 8; dt++) {
        bf16x8 vf = *(const bf16x8*)&lV[dt * 16 + lr][lk8];
        o[dt] = __builtin_amdgcn_mfma_f32_16x16x32_bf16(pf, vf, o[dt], 0, 0, 0);
      }
    }
    __syncthreads();
  }
  // epilogue: divide by l, write (B,T,C) bf16
  for (int r = 0; r < 4; r++) {
    float inv = 1.0f / l[r];
    int qg = qbase + (lane >> 4) * 4 + r;
    size_t obase = ((size_t)b * T_ + qg) * C_ + (size_t)h * HD_;
    for (int dt = 0; dt < 8; dt++)
      Out[obase + dt * 16 + lr] = f2bf(o[dt][r] * inv);
  }
}

// ---------------- launch --------------------------------------------------
extern "C" void kernel_launch(void* const* d_in, const int* in_sizes, int n_in,
                              void* d_out, int out_size, void* d_ws,
                              size_t ws_size, hipStream_t stream) {
  (void)in_sizes; (void)n_in; (void)out_size; (void)ws_size;
  const float* x = (const float*)d_in[0];
  const float* cosb = (const float*)d_in[1];
  const float* sinb = (const float*)d_in[2];
  const float* w_qkv = (const float*)d_in[3];
  const float* w_proj = (const float*)d_in[4];

  char* ws = (char*)d_ws;
  // layout (bytes): wqkvb 25165824 | wprojb 8388608 | xb 16777216 |
  //                 qkv 50331648 | kr 16777216 | vr 16777216   = 128 MiB
  ushort* wqkvb = (ushort*)(ws);
  ushort* wprojb = (ushort*)(ws + 25165824);
  ushort* xb = (ushort*)(ws + 25165824 + 8388608);
  ushort* qkv = (ushort*)(ws + 25165824 + 8388608 + 16777216);
  ushort* kr = (ushort*)(ws + 25165824 + 8388608 + 16777216 + 50331648);
  ushort* vr = (ushort*)(ws + 25165824 + 8388608 + 16777216 + 50331648 + 16777216);
  ushort* qr = xb;        // alias: xb dead after GEMM1
  ushort* attn_out = qkv; // alias: qkv dead after rope_split

  k_f2bf<<<8192, 256, 0, stream>>>(x, xb, 2097152);
  k_f2bf<<<12288, 256, 0, stream>>>(w_qkv, wqkvb, 3145728);
  k_f2bf<<<4096, 256, 0, stream>>>(w_proj, wprojb, 1048576);

  // qkv = x @ w_qkv^T : M=4096, N=6144, K=2048
  gemm_bt<1><<<dim3(48, 32), 256, 0, stream>>>(xb, wqkvb, (void*)qkv,
                                               4096, 6144, 2048);
  rope_split<<<4096, 256, 0, stream>>>(qkv, cosb, sinb, qr, kr, vr);
  attn_fwd<<<dim3(32, 32), 256, 0, stream>>>(qr, kr, vr, attn_out);
  // out = attn_out @ w_proj^T : M=4096, N=2048, K=2048
  gemm_bt<0><<<dim3(16, 32), 256, 0, stream>>>(attn_out, wprojb, d_out,
                                               4096, 2048, 2048);
}

// Round 2
// 499.102 us; speedup vs baseline: 1.5284x; 1.5284x over previous
//
#include <hip/hip_runtime.h>
#include <hip/hip_bf16.h>
#include <stdint.h>

typedef __attribute__((ext_vector_type(8))) short bf16x8;
typedef __attribute__((ext_vector_type(4))) float f32x4;

#define B_ 2
#define T_ 2048
#define C_ 2048
#define H_ 16
#define HD_ 128

__device__ inline ushort f2bf(float f) {
  union { float f; uint32_t u; } v; v.f = f;
  uint32_t u = v.u;
  uint32_t r = (u + 0x7fffu + ((u >> 16) & 1u)) >> 16;
  return (ushort)r;
}
__device__ inline float bf2f(ushort h) {
  union { uint32_t u; float f; } v; v.u = ((uint32_t)h) << 16;
  return v.f;
}

typedef const __attribute__((address_space(1))) void* gas1_t;
typedef __attribute__((address_space(3))) void* las3_t;
__device__ inline void gld_lds16(const void* g, void* l) {
  __builtin_amdgcn_global_load_lds((gas1_t)g, (las3_t)l, 16, 0, 0);
}

// ---------------- fp32 -> bf16 conversion ----------------
__global__ __launch_bounds__(256) void k_f2bf(const float* __restrict__ in,
                                              ushort* __restrict__ out, int n4) {
  int i = blockIdx.x * 256 + threadIdx.x;
  if (i < n4) {
    f32x4 v = *(const f32x4*)(in + (size_t)i * 4);
    ushort4 o;
    o.x = f2bf(v[0]); o.y = f2bf(v[1]); o.z = f2bf(v[2]); o.w = f2bf(v[3]);
    *(ushort4*)(out + (size_t)i * 4) = o;
  }
}

// ---------------- GEMM: C[M,N] = A[M,K] * B[N,K]^T (bf16 in, f32 acc) -----
// 128x128 tile, BK=32, 4 waves (2x2 of 64x64), 16x16x32 bf16 MFMA,
// global_load_lds(16B) staging, double-buffered LDS, 2-barrier/K-step.
template <int OUT_BF16>
__global__ __launch_bounds__(256)
void gemm_bt(const ushort* __restrict__ A, const ushort* __restrict__ Bm,
             void* __restrict__ Cout, int M, int N, int K) {
  __shared__ ushort lA[2][128 * 32];
  __shared__ ushort lB[2][128 * 32];
  const int tid = threadIdx.x;
  const int wid = tid >> 6, lane = tid & 63;
  const int bx = blockIdx.x, by = blockIdx.y;
  const size_t rowA0 = (size_t)by * 128, colB0 = (size_t)bx * 128;
  const int sr = lane >> 2, sc = (lane & 3) * 8;

  const ushort* Abase = A + rowA0 * K + sc;
  const ushort* Bbase = Bm + colB0 * K + sc;

  auto stage = [&](int buf, int kt) {
    const ushort* Ak = Abase + (size_t)kt * 32;
    const ushort* Bk = Bbase + (size_t)kt * 32;
    for (int i = 0; i < 2; i++) {
      int chunk = wid * 2 + i;           // this wave's 1KB chunks
      int row = chunk * 16 + sr;         // 16 rows per chunk, 4 lanes/row
      gld_lds16(Ak + (size_t)row * K, &lA[buf][chunk * 512]);
      gld_lds16(Bk + (size_t)row * K, &lB[buf][chunk * 512]);
    }
  };

  f32x4 acc[4][4];
  const f32x4 zf = {0.f, 0.f, 0.f, 0.f};
  for (int i = 0; i < 4; i++)
    for (int j = 0; j < 4; j++) acc[i][j] = zf;

  const int wr = (wid >> 1) * 64, wc = (wid & 1) * 64;
  const int lr = lane & 15, lk = (lane >> 4) * 8;

  stage(0, 0);
  __syncthreads();
  const int NT = K / 32;
  int buf = 0;
  for (int kt = 0; kt < NT; kt++) {
    if (kt + 1 < NT) stage(buf ^ 1, kt + 1);
    bf16x8 af[4], bfr[4];
    for (int i = 0; i < 4; i++)
      af[i] = *(const bf16x8*)&lA[buf][(wr + i * 16 + lr) * 32 + lk];
    for (int j = 0; j < 4; j++)
      bfr[j] = *(const bf16x8*)&lB[buf][(wc + j * 16 + lr) * 32 + lk];
    for (int i = 0; i < 4; i++)
      for (int j = 0; j < 4; j++)
        acc[i][j] = __builtin_amdgcn_mfma_f32_16x16x32_bf16(af[i], bfr[j],
                                                            acc[i][j], 0, 0, 0);
    __syncthreads();
    buf ^= 1;
  }
  const int lq = (lane >> 4) * 4;
  for (int i = 0; i < 4; i++)
    for (int j = 0; j < 4; j++)
      for (int r = 0; r < 4; r++) {
        size_t row = rowA0 + wr + i * 16 + lq + r;
        size_t col = colB0 + wc + j * 16 + lr;
        float v = acc[i][j][r];
        if (OUT_BF16)
          ((ushort*)Cout)[row * (size_t)N + col] = f2bf(v);
        else
          ((float*)Cout)[row * (size_t)N + col] = v;
      }
}

// ---------------- RoPE + split to (B,H,T,hd), scale Q by 1/sqrt(hd) -------
__global__ __launch_bounds__(256)
void rope_split(const ushort* __restrict__ qkv, const float* __restrict__ cosb,
                const float* __restrict__ sinb, ushort* __restrict__ Qr,
                ushort* __restrict__ Kr, ushort* __restrict__ Vr) {
  const int bt = blockIdx.x;
  const int b = bt >> 11, t = bt & 2047;
  const ushort* base = qkv + (size_t)bt * (3 * C_);
  const int tid = threadIdx.x;
  const float rs = 0.08838834764831845f;  // 1/sqrt(128)
  for (int i = 0; i < 4; i++) {
    int idx = tid + i * 256;  // 0..1023 = (h, pair)
    int h = idx >> 6, p = idx & 63;
    float c = cosb[t * 64 + p], s = sinb[t * 64 + p];
    size_t src = (size_t)h * HD_ + 2 * p;
    size_t dst = (((size_t)(b * H_ + h)) * T_ + t) * HD_ + 2 * p;
    // q (rotated + scaled)
    float x1 = bf2f(base[src]), x2 = bf2f(base[src + 1]);
    Qr[dst] = f2bf((x1 * c - x2 * s) * rs);
    Qr[dst + 1] = f2bf((x1 * s + x2 * c) * rs);
    // k (rotated)
    x1 = bf2f(base[C_ + src]); x2 = bf2f(base[C_ + src + 1]);
    Kr[dst] = f2bf(x1 * c - x2 * s);
    Kr[dst + 1] = f2bf(x1 * s + x2 * c);
    // v (copy)
    Vr[dst] = base[2 * C_ + src];
    Vr[dst + 1] = base[2 * C_ + src + 1];
  }
}

// ---------------- causal flash attention ---------------------------------
// grid (32, B*H), 256 threads = 4 waves, each wave owns 16 q rows.
// q-tile swizzled (bx+by)&31 for per-CU causal load balance.
// KV tile = 32 rows. K row-major padded; V transposed in LDS (split chunk
// mapping -> 4-way instead of 16-way write conflicts); T14 async staging.
__global__ __launch_bounds__(256)
void attn_fwd(const ushort* __restrict__ Qr, const ushort* __restrict__ Kr,
              const ushort* __restrict__ Vr, ushort* __restrict__ Out) {
  __shared__ ushort lK[32][136];    // +16B pad per row
  __shared__ ushort lV[128][40];    // transposed: lV[d][k], +16B pad
  __shared__ ushort lP[4][16][40];  // per-wave P tile
  const int tid = threadIdx.x, wid = tid >> 6, lane = tid & 63;
  const int bh = blockIdx.y;
  const int b = bh >> 4, h = bh & 15;
  const int qt = (blockIdx.x + blockIdx.y) & 31;  // balance: CU gets mixed tiles
  const int qbase = qt * 64 + wid * 16;
  const int lr = lane & 15, lk8 = (lane >> 4) * 8;

  const ushort* Qp = Qr + ((size_t)bh * T_ + qbase) * HD_;
  const ushort* Kp = Kr + (size_t)bh * T_ * HD_;
  const ushort* Vp = Vr + (size_t)bh * T_ * HD_;

  bf16x8 qf[4];
  for (int dc = 0; dc < 4; dc++)
    qf[dc] = *(const bf16x8*)(Qp + (size_t)lr * HD_ + dc * 32 + lk8);

  f32x4 o[8];
  const f32x4 zf = {0.f, 0.f, 0.f, 0.f};
  for (int dt = 0; dt < 8; dt++) o[dt] = zf;
  float m[4], l[4];
  for (int r = 0; r < 4; r++) { m[r] = -1e30f; l[r] = 0.f; }

  // staging coords (deterministic from tid): K row-major, V split mapping
  int rK[2], cK[2], rV[2], cV[2];
  for (int i = 0; i < 2; i++) {
    int chunk = tid + i * 256;            // 512 chunks of 8 elements
    rK[i] = chunk >> 4; cK[i] = (chunk & 15) * 8;
    rV[i] = chunk & 31; cV[i] = (chunk >> 5) * 8;
  }

  bf16x8 kreg[2], vreg[2];
  auto load_tile = [&](int kt) {
    for (int i = 0; i < 2; i++) {
      kreg[i] = *(const bf16x8*)(Kp + ((size_t)(kt * 32 + rK[i])) * HD_ + cK[i]);
      vreg[i] = *(const bf16x8*)(Vp + ((size_t)(kt * 32 + rV[i])) * HD_ + cV[i]);
    }
  };

  const int nkt = 2 * qt + 2;  // kv tiles this q-tile needs (causal)
  load_tile(0);
  for (int kt = 0; kt < nkt; kt++) {
    __syncthreads();  // previous tile's compute done reading LDS
    for (int i = 0; i < 2; i++) {
      *(bf16x8*)&lK[rK[i]][cK[i]] = kreg[i];
      for (int j = 0; j < 8; j++) lV[cV[i] + j][rV[i]] = (ushort)vreg[i][j];
    }
    if (kt + 1 < nkt) load_tile(kt + 1);  // T14: overlap with compute below
    __syncthreads();
    if (kt * 32 <= qbase + 15) {  // wave participates in this tile
      f32x4 s[2];
      for (int kn = 0; kn < 2; kn++) {
        f32x4 a = zf;
        for (int dc = 0; dc < 4; dc++) {
          bf16x8 kf = *(const bf16x8*)&lK[kn * 16 + lr][dc * 32 + lk8];
          a = __builtin_amdgcn_mfma_f32_16x16x32_bf16(qf[dc], kf, a, 0, 0, 0);
        }
        s[kn] = a;
      }
      // causal mask (C layout: col=lane&15 -> k, row=(lane>>4)*4+r -> q)
      const int qrow = qbase + (lane >> 4) * 4;
      for (int kn = 0; kn < 2; kn++) {
        int kg = kt * 32 + kn * 16 + lr;
        for (int r = 0; r < 4; r++)
          if (kg > qrow + r) s[kn][r] = -1e30f;
      }
      // online softmax (row-reduce across the 16-lane group)
      float al[4];
      for (int r = 0; r < 4; r++) {
        float pm = fmaxf(s[0][r], s[1][r]);
        for (int off = 1; off < 16; off <<= 1)
          pm = fmaxf(pm, __shfl_xor(pm, off, 64));
        float mn = fmaxf(m[r], pm);
        float a = __expf(m[r] - mn);
        float p0 = __expf(s[0][r] - mn);
        float p1 = __expf(s[1][r] - mn);
        s[0][r] = p0; s[1][r] = p1;
        float rsum = p0 + p1;
        for (int off = 1; off < 16; off <<= 1)
          rsum += __shfl_xor(rsum, off, 64);
        l[r] = l[r] * a + rsum;
        m[r] = mn;
        al[r] = a;
      }
      for (int dt = 0; dt < 8; dt++)
        for (int r = 0; r < 4; r++) o[dt][r] *= al[r];
      // P (C layout) -> LDS -> A-frag layout
      for (int kn = 0; kn < 2; kn++)
        for (int r = 0; r < 4; r++)
          lP[wid][(lane >> 4) * 4 + r][kn * 16 + lr] = f2bf(s[kn][r]);
      bf16x8 pf = *(const bf16x8*)&lP[wid][lr][lk8];
      for (int dt = 0; dt < 8; dt++) {
        bf16x8 vf = *(const bf16x8*)&lV[dt * 16 + lr][lk8];
        o[dt] = __builtin_amdgcn_mfma_f32_16x16x32_bf16(pf, vf, o[dt], 0, 0, 0);
      }
    }
  }
  // epilogue: divide by l, write (B,T,C) bf16
  for (int r = 0; r < 4; r++) {
    float inv = 1.0f / l[r];
    int qg = qbase + (lane >> 4) * 4 + r;
    size_t obase = ((size_t)b * T_ + qg) * C_ + (size_t)h * HD_;
    for (int dt = 0; dt < 8; dt++)
      Out[obase + dt * 16 + lr] = f2bf(o[dt][r] * inv);
  }
}

// ---------------- launch --------------------------------------------------
extern "C" void kernel_launch(void* const* d_in, const int* in_sizes, int n_in,
                              void* d_out, int out_size, void* d_ws,
                              size_t ws_size, hipStream_t stream) {
  (void)in_sizes; (void)n_in; (void)out_size; (void)ws_size;
  const float* x = (const float*)d_in[0];
  const float* cosb = (const float*)d_in[1];
  const float* sinb = (const float*)d_in[2];
  const float* w_qkv = (const float*)d_in[3];
  const float* w_proj = (const float*)d_in[4];

  char* ws = (char*)d_ws;
  // layout (bytes): wqkvb 25165824 | wprojb 8388608 | xb 16777216 |
  //                 qkv 50331648 | kr 16777216 | vr 16777216   = 128 MiB
  ushort* wqkvb = (ushort*)(ws);
  ushort* wprojb = (ushort*)(ws + 25165824);
  ushort* xb = (ushort*)(ws + 25165824 + 8388608);
  ushort* qkv = (ushort*)(ws + 25165824 + 8388608 + 16777216);
  ushort* kr = (ushort*)(ws + 25165824 + 8388608 + 16777216 + 50331648);
  ushort* vr = (ushort*)(ws + 25165824 + 8388608 + 16777216 + 50331648 + 16777216);
  ushort* qr = xb;        // alias: xb dead after GEMM1
  ushort* attn_out = qkv; // alias: qkv dead after rope_split

  k_f2bf<<<8192, 256, 0, stream>>>(x, xb, 2097152);
  k_f2bf<<<12288, 256, 0, stream>>>(w_qkv, wqkvb, 3145728);
  k_f2bf<<<4096, 256, 0, stream>>>(w_proj, wprojb, 1048576);

  // qkv = x @ w_qkv^T : M=4096, N=6144, K=2048
  gemm_bt<1><<<dim3(48, 32), 256, 0, stream>>>(xb, wqkvb, (void*)qkv,
                                               4096, 6144, 2048);
  rope_split<<<4096, 256, 0, stream>>>(qkv, cosb, sinb, qr, kr, vr);
  attn_fwd<<<dim3(32, 32), 256, 0, stream>>>(qr, kr, vr, attn_out);
  // out = attn_out @ w_proj^T : M=4096, N=2048, K=2048
  gemm_bt<0><<<dim3(16, 32), 256, 0, stream>>>(attn_out, wprojb, d_out,
                                               4096, 2048, 2048);
}

// Round 3
// 410.840 us; speedup vs baseline: 1.8567x; 1.2148x over previous
//
#include <hip/hip_runtime.h>
#include <hip/hip_bf16.h>
#include <stdint.h>

typedef __attribute__((ext_vector_type(8))) short bf16x8;
typedef __attribute__((ext_vector_type(4))) float f32x4;

#define B_ 2
#define T_ 2048
#define C_ 2048
#define H_ 16
#define HD_ 128

__device__ inline ushort f2bf(float f) {
  union { float f; uint32_t u; } v; v.f = f;
  uint32_t u = v.u;
  uint32_t r = (u + 0x7fffu + ((u >> 16) & 1u)) >> 16;
  return (ushort)r;
}
__device__ inline float bf2f(ushort h) {
  union { uint32_t u; float f; } v; v.u = ((uint32_t)h) << 16;
  return v.f;
}

typedef const __attribute__((address_space(1))) void* gas1_t;
typedef __attribute__((address_space(3))) void* las3_t;
__device__ inline void gld_lds16(const void* g, void* l) {
  __builtin_amdgcn_global_load_lds((gas1_t)g, (las3_t)l, 16, 0, 0);
}

// ---------------- fp32 -> bf16 conversion ----------------
__global__ __launch_bounds__(256) void k_f2bf(const float* __restrict__ in,
                                              ushort* __restrict__ out, int n4) {
  int i = blockIdx.x * 256 + threadIdx.x;
  if (i < n4) {
    f32x4 v = *(const f32x4*)(in + (size_t)i * 4);
    ushort4 o;
    o.x = f2bf(v[0]); o.y = f2bf(v[1]); o.z = f2bf(v[2]); o.w = f2bf(v[3]);
    *(ushort4*)(out + (size_t)i * 4) = o;
  }
}

// ---------------- GEMM: C[M,N] = A[M,K] * B[N,K]^T (bf16 in, f32 acc) -----
// 128x128 tile, BK=32, 4 waves (2x2 of 64x64), 16x16x32 bf16 MFMA,
// global_load_lds(16B) staging, double-buffered LDS, 2-barrier/K-step.
template <int OUT_BF16>
__global__ __launch_bounds__(256)
void gemm_bt(const ushort* __restrict__ A, const ushort* __restrict__ Bm,
             void* __restrict__ Cout, int M, int N, int K) {
  __shared__ ushort lA[2][128 * 32];
  __shared__ ushort lB[2][128 * 32];
  const int tid = threadIdx.x;
  const int wid = tid >> 6, lane = tid & 63;
  const int bx = blockIdx.x, by = blockIdx.y;
  const size_t rowA0 = (size_t)by * 128, colB0 = (size_t)bx * 128;
  const int sr = lane >> 2, sc = (lane & 3) * 8;

  const ushort* Abase = A + rowA0 * K + sc;
  const ushort* Bbase = Bm + colB0 * K + sc;

  auto stage = [&](int buf, int kt) {
    const ushort* Ak = Abase + (size_t)kt * 32;
    const ushort* Bk = Bbase + (size_t)kt * 32;
    for (int i = 0; i < 2; i++) {
      int chunk = wid * 2 + i;           // this wave's 1KB chunks
      int row = chunk * 16 + sr;         // 16 rows per chunk, 4 lanes/row
      gld_lds16(Ak + (size_t)row * K, &lA[buf][chunk * 512]);
      gld_lds16(Bk + (size_t)row * K, &lB[buf][chunk * 512]);
    }
  };

  f32x4 acc[4][4];
  const f32x4 zf = {0.f, 0.f, 0.f, 0.f};
  for (int i = 0; i < 4; i++)
    for (int j = 0; j < 4; j++) acc[i][j] = zf;

  const int wr = (wid >> 1) * 64, wc = (wid & 1) * 64;
  const int lr = lane & 15, lk = (lane >> 4) * 8;

  stage(0, 0);
  __syncthreads();
  const int NT = K / 32;
  int buf = 0;
  for (int kt = 0; kt < NT; kt++) {
    if (kt + 1 < NT) stage(buf ^ 1, kt + 1);
    bf16x8 af[4], bfr[4];
    for (int i = 0; i < 4; i++)
      af[i] = *(const bf16x8*)&lA[buf][(wr + i * 16 + lr) * 32 + lk];
    for (int j = 0; j < 4; j++)
      bfr[j] = *(const bf16x8*)&lB[buf][(wc + j * 16 + lr) * 32 + lk];
    for (int i = 0; i < 4; i++)
      for (int j = 0; j < 4; j++)
        acc[i][j] = __builtin_amdgcn_mfma_f32_16x16x32_bf16(af[i], bfr[j],
                                                            acc[i][j], 0, 0, 0);
    __syncthreads();
    buf ^= 1;
  }
  const int lq = (lane >> 4) * 4;
  for (int i = 0; i < 4; i++)
    for (int j = 0; j < 4; j++)
      for (int r = 0; r < 4; r++) {
        size_t row = rowA0 + wr + i * 16 + lq + r;
        size_t col = colB0 + wc + j * 16 + lr;
        float v = acc[i][j][r];
        if (OUT_BF16)
          ((ushort*)Cout)[row * (size_t)N + col] = f2bf(v);
        else
          ((float*)Cout)[row * (size_t)N + col] = v;
      }
}

// ---------------- RoPE + split to (B,H,T,hd), scale Q by 1/sqrt(hd) -------
__global__ __launch_bounds__(256)
void rope_split(const ushort* __restrict__ qkv, const float* __restrict__ cosb,
                const float* __restrict__ sinb, ushort* __restrict__ Qr,
                ushort* __restrict__ Kr, ushort* __restrict__ Vr) {
  const int bt = blockIdx.x;
  const int b = bt >> 11, t = bt & 2047;
  const ushort* base = qkv + (size_t)bt * (3 * C_);
  const int tid = threadIdx.x;
  const float rs = 0.08838834764831845f;  // 1/sqrt(128)
  for (int i = 0; i < 4; i++) {
    int idx = tid + i * 256;  // 0..1023 = (h, pair)
    int h = idx >> 6, p = idx & 63;
    float c = cosb[t * 64 + p], s = sinb[t * 64 + p];
    size_t src = (size_t)h * HD_ + 2 * p;
    size_t dst = (((size_t)(b * H_ + h)) * T_ + t) * HD_ + 2 * p;
    // q (rotated + scaled)
    float x1 = bf2f(base[src]), x2 = bf2f(base[src + 1]);
    Qr[dst] = f2bf((x1 * c - x2 * s) * rs);
    Qr[dst + 1] = f2bf((x1 * s + x2 * c) * rs);
    // k (rotated)
    x1 = bf2f(base[C_ + src]); x2 = bf2f(base[C_ + src + 1]);
    Kr[dst] = f2bf(x1 * c - x2 * s);
    Kr[dst + 1] = f2bf(x1 * s + x2 * c);
    // v (copy)
    Vr[dst] = base[2 * C_ + src];
    Vr[dst + 1] = base[2 * C_ + src + 1];
  }
}

// ---------------- causal flash attention ---------------------------------
// grid (16, B*H), 256 threads = 4 waves, each wave owns 16 q rows.
// Each block processes the PAIR of q-tiles (pr, 31-pr) sequentially ->
// every block does exactly 68 KV-tile-units (perfect causal balance).
// Swapped QK^T: mfma(K,Q) puts a full q-row per lane -> softmax reductions
// are 2 shuffles for all 16 rows. PV computed as O^T = mfma(V^T, P).
// KV tile = 32 rows; T14 async staging; T13 defer-max (THR=5).
__global__ __launch_bounds__(256)
void attn_fwd(const ushort* __restrict__ Qr, const ushort* __restrict__ Kr,
              const ushort* __restrict__ Vr, ushort* __restrict__ Out) {
  __shared__ ushort lK[32][136];    // +16B pad per row (16B-aligned rows)
  __shared__ ushort lV[128][40];    // transposed: lV[d][k], +16B pad
  __shared__ ushort lP[4][16][40];  // per-wave P tile (A-frag staging)
  const int tid = threadIdx.x, wid = tid >> 6, lane = tid & 63;
  const int bh = blockIdx.y;
  const int b = bh >> 4, h = bh & 15;
  const int pr = blockIdx.x;  // 0..15 -> q-tiles {pr, 31-pr}
  const int lr = lane & 15, g = lane >> 4, lk8 = g * 8;
  const f32x4 zf = {0.f, 0.f, 0.f, 0.f};

  const ushort* Kp = Kr + (size_t)bh * T_ * HD_;
  const ushort* Vp = Vr + (size_t)bh * T_ * HD_;

  // staging coords (deterministic from tid): K row-major, V split mapping
  int rK[2], cK[2], rV[2], cV[2];
  for (int i = 0; i < 2; i++) {
    int chunk = tid + i * 256;            // 512 chunks of 8 elements
    rK[i] = chunk >> 4; cK[i] = (chunk & 15) * 8;
    rV[i] = chunk & 31; cV[i] = (chunk >> 5) * 8;
  }

  for (int seg = 0; seg < 2; ++seg) {
    const int qt = seg ? (31 - pr) : pr;
    const int qbase = qt * 64 + wid * 16;
    const ushort* Qp = Qr + ((size_t)bh * T_ + qbase) * HD_;

    bf16x8 qf[4];
    for (int dc = 0; dc < 4; dc++)
      qf[dc] = *(const bf16x8*)(Qp + (size_t)lr * HD_ + dc * 32 + lk8);

    f32x4 o[8];
    for (int dt = 0; dt < 8; dt++) o[dt] = zf;
    float m = -1e30f, l = 0.f;

    bf16x8 kreg[2], vreg[2];
    auto load_tile = [&](int kt) {
      for (int i = 0; i < 2; i++) {
        kreg[i] = *(const bf16x8*)(Kp + ((size_t)(kt * 32 + rK[i])) * HD_ + cK[i]);
        vreg[i] = *(const bf16x8*)(Vp + ((size_t)(kt * 32 + rV[i])) * HD_ + cV[i]);
      }
    };

    const int nkt = 2 * qt + 2;  // kv tiles this q-tile needs (causal)
    load_tile(0);
    for (int kt = 0; kt < nkt; kt++) {
      __syncthreads();  // previous tile's compute done reading LDS
      for (int i = 0; i < 2; i++) {
        *(bf16x8*)&lK[rK[i]][cK[i]] = kreg[i];
        for (int j = 0; j < 8; j++) lV[cV[i] + j][rV[i]] = (ushort)vreg[i][j];
      }
      if (kt + 1 < nkt) load_tile(kt + 1);  // T14: overlap with compute below
      __syncthreads();
      if (kt * 32 <= qbase + 15) {  // wave participates in this tile
        // swapped QK^T: lane holds S[q = qbase+lr][k = kt*32 + kn*16 + g*4 + r]
        f32x4 s[2];
        for (int kn = 0; kn < 2; kn++) {
          f32x4 a = zf;
          for (int dc = 0; dc < 4; dc++) {
            bf16x8 kf = *(const bf16x8*)&lK[kn * 16 + lr][dc * 32 + lk8];
            a = __builtin_amdgcn_mfma_f32_16x16x32_bf16(kf, qf[dc], a, 0, 0, 0);
          }
          s[kn] = a;
        }
        const int qg = qbase + lr;
        if (kt * 32 + 31 > qbase) {  // tile touches the diagonal
          for (int kn = 0; kn < 2; kn++) {
            int k0 = kt * 32 + kn * 16 + g * 4;
            for (int r = 0; r < 4; r++)
              if (k0 + r > qg) s[kn][r] = -1e30f;
          }
        }
        // per-lane row max over 8 in-register values + 2 shuffles
        float pm = fmaxf(fmaxf(fmaxf(s[0][0], s[0][1]), fmaxf(s[0][2], s[0][3])),
                         fmaxf(fmaxf(s[1][0], s[1][1]), fmaxf(s[1][2], s[1][3])));
        pm = fmaxf(pm, __shfl_xor(pm, 16, 64));
        pm = fmaxf(pm, __shfl_xor(pm, 32, 64));
        // T13 defer-max: only rescale when max grew beyond threshold
        if (!__all(pm - m <= 5.0f)) {
          float mn = fmaxf(m, pm);
          float a = __expf(m - mn);
          for (int dt = 0; dt < 8; dt++)
            for (int r = 0; r < 4; r++) o[dt][r] *= a;
          l *= a;
          m = mn;
        }
        float p[8];
        float rsum = 0.f;
        for (int kn = 0; kn < 2; kn++)
          for (int r = 0; r < 4; r++) {
            float pv = __expf(s[kn][r] - m);
            p[kn * 4 + r] = pv;
            rsum += pv;
          }
        rsum += __shfl_xor(rsum, 16, 64);
        rsum += __shfl_xor(rsum, 32, 64);
        l += rsum;
        // P -> LDS (arrange as B-frag rows: lane q=lr reads k=g*8..g*8+7)
        for (int kn = 0; kn < 2; kn++) {
          ushort2 w0, w1;
          w0.x = f2bf(p[kn * 4 + 0]); w0.y = f2bf(p[kn * 4 + 1]);
          w1.x = f2bf(p[kn * 4 + 2]); w1.y = f2bf(p[kn * 4 + 3]);
          *(ushort2*)&lP[wid][lr][kn * 16 + g * 4] = w0;
          *(ushort2*)&lP[wid][lr][kn * 16 + g * 4 + 2] = w1;
        }
        bf16x8 pf = *(const bf16x8*)&lP[wid][lr][lk8];
        // O^T accumulate: D[d][q] = sum_k V^T[d,k] * P[q,k]
        for (int dt = 0; dt < 8; dt++) {
          bf16x8 vf = *(const bf16x8*)&lV[dt * 16 + lr][lk8];
          o[dt] = __builtin_amdgcn_mfma_f32_16x16x32_bf16(vf, pf, o[dt], 0, 0, 0);
        }
      }
    }
    // epilogue: lane owns q = qbase+lr, d = dt*16 + g*4 + r
    float inv = 1.0f / l;
    int qg = qbase + lr;
    size_t obase = ((size_t)b * T_ + qg) * C_ + (size_t)h * HD_;
    for (int dt = 0; dt < 8; dt++) {
      ushort4 w;
      w.x = f2bf(o[dt][0] * inv);
      w.y = f2bf(o[dt][1] * inv);
      w.z = f2bf(o[dt][2] * inv);
      w.w = f2bf(o[dt][3] * inv);
      *(ushort4*)&Out[obase + dt * 16 + g * 4] = w;
    }
  }
}

// ---------------- launch --------------------------------------------------
extern "C" void kernel_launch(void* const* d_in, const int* in_sizes, int n_in,
                              void* d_out, int out_size, void* d_ws,
                              size_t ws_size, hipStream_t stream) {
  (void)in_sizes; (void)n_in; (void)out_size; (void)ws_size;
  const float* x = (const float*)d_in[0];
  const float* cosb = (const float*)d_in[1];
  const float* sinb = (const float*)d_in[2];
  const float* w_qkv = (const float*)d_in[3];
  const float* w_proj = (const float*)d_in[4];

  char* ws = (char*)d_ws;
  // layout (bytes): wqkvb 25165824 | wprojb 8388608 | xb 16777216 |
  //                 qkv 50331648 | kr 16777216 | vr 16777216   = 128 MiB
  ushort* wqkvb = (ushort*)(ws);
  ushort* wprojb = (ushort*)(ws + 25165824);
  ushort* xb = (ushort*)(ws + 25165824 + 8388608);
  ushort* qkv = (ushort*)(ws + 25165824 + 8388608 + 16777216);
  ushort* kr = (ushort*)(ws + 25165824 + 8388608 + 16777216 + 50331648);
  ushort* vr = (ushort*)(ws + 25165824 + 8388608 + 16777216 + 50331648 + 16777216);
  ushort* qr = xb;        // alias: xb dead after GEMM1
  ushort* attn_out = qkv; // alias: qkv dead after rope_split

  k_f2bf<<<8192, 256, 0, stream>>>(x, xb, 2097152);
  k_f2bf<<<12288, 256, 0, stream>>>(w_qkv, wqkvb, 3145728);
  k_f2bf<<<4096, 256, 0, stream>>>(w_proj, wprojb, 1048576);

  // qkv = x @ w_qkv^T : M=4096, N=6144, K=2048
  gemm_bt<1><<<dim3(48, 32), 256, 0, stream>>>(xb, wqkvb, (void*)qkv,
                                               4096, 6144, 2048);
  rope_split<<<4096, 256, 0, stream>>>(qkv, cosb, sinb, qr, kr, vr);
  attn_fwd<<<dim3(16, 32), 256, 0, stream>>>(qr, kr, vr, attn_out);
  // out = attn_out @ w_proj^T : M=4096, N=2048, K=2048
  gemm_bt<0><<<dim3(16, 32), 256, 0, stream>>>(attn_out, wprojb, d_out,
                                               4096, 2048, 2048);
}

// Round 4
// 410.717 us; speedup vs baseline: 1.8573x; 1.0003x over previous
//
#include <hip/hip_runtime.h>
#include <hip/hip_bf16.h>
#include <stdint.h>

typedef __attribute__((ext_vector_type(8))) short bf16x8;
typedef __attribute__((ext_vector_type(4))) float f32x4;

#define B_ 2
#define T_ 2048
#define C_ 2048
#define H_ 16
#define HD_ 128

#define MFENCE asm volatile("" ::: "memory")

__device__ inline ushort f2bf(float f) {
  union { float f; uint32_t u; } v; v.f = f;
  uint32_t u = v.u;
  uint32_t r = (u + 0x7fffu + ((u >> 16) & 1u)) >> 16;
  return (ushort)r;
}
__device__ inline float bf2f(ushort h) {
  union { uint32_t u; float f; } v; v.u = ((uint32_t)h) << 16;
  return v.f;
}

typedef const __attribute__((address_space(1))) void* gas1_t;
typedef __attribute__((address_space(3))) void* las3_t;
__device__ inline void gld_lds16(const void* g, void* l) {
  __builtin_amdgcn_global_load_lds((gas1_t)g, (las3_t)l, 16, 0, 0);
}

// ---------------- fp32 -> bf16 conversion ----------------
__global__ __launch_bounds__(256) void k_f2bf(const float* __restrict__ in,
                                              ushort* __restrict__ out, int n4) {
  int i = blockIdx.x * 256 + threadIdx.x;
  if (i < n4) {
    f32x4 v = *(const f32x4*)(in + (size_t)i * 4);
    ushort4 o;
    o.x = f2bf(v[0]); o.y = f2bf(v[1]); o.z = f2bf(v[2]); o.w = f2bf(v[3]);
    *(ushort4*)(out + (size_t)i * 4) = o;
  }
}

// ============ 256x256 8-phase GEMM: C[M,N] = A[M,K] * B[N,K]^T, bf16 out ===
// BK=32, 512 threads = 8 waves (2M x 4N), striped frags (row = mf*32+wm*16).
// 2 phases per K-tile, 16 MFMA per phase, counted vmcnt(2) at tile boundary,
// row-pair XOR swizzle on LDS (inverse applied on global source), setprio.
__global__ __launch_bounds__(512, 2)
void gemm256(const ushort* __restrict__ A, const ushort* __restrict__ Bm,
             ushort* __restrict__ Cout, int M, int N, int K) {
  __shared__ ushort lds[2][16384];  // per buf: Ah0|Ah1|Bh0|Bh1, 8 KiB each
  const int tid = threadIdx.x;
  const int wid = tid >> 6, lane = tid & 63;
  const int wm = wid >> 2, wn = wid & 3;

  // XCD-aware flat swizzle (384 % 8 == 0 -> bijective)
  const int nwg = gridDim.x;
  const int cpx = nwg >> 3;
  const int bid = blockIdx.x;
  const int wg = (bid & 7) * cpx + (bid >> 3);
  const int ntx = N >> 8;            // n-tiles
  const int bm = wg / ntx, bn = wg % ntx;
  const size_t trow0 = (size_t)bm * 256, tcol0 = (size_t)bn * 256;

  // ---- per-thread staging source (inverse-swizzled global address) ----
  const size_t Kb = (size_t)K * 2;   // row stride in bytes
  {
  }
  const int s = tid * 16;
  const int rp = s >> 7;
  const int sub = (s & 127) ^ ((rp & 7) << 4);
  const int r_st = rp * 2 + (sub >> 6);
  const int kb_st = sub & 63;
  const char* aSrc = (const char*)A + (trow0 + r_st) * Kb + kb_st;
  const char* bSrc = (const char*)Bm + (tcol0 + r_st) * Kb + kb_st;

  auto stA = [&](int bf, int h, int kt) {
    gld_lds16(aSrc + (size_t)h * 128 * Kb + (size_t)kt * 64,
              &lds[bf][h * 4096 + wid * 512]);
  };
  auto stB = [&](int bf, int h, int kt) {
    gld_lds16(bSrc + (size_t)h * 128 * Kb + (size_t)kt * 64,
              &lds[bf][8192 + h * 4096 + wid * 512]);
  };

  // ---- per-lane ds_read offsets (swizzled, ushort units) ----
  int aOff[8], bOff[4];
  {
    const int li = lane & 15, cb = (lane >> 4) * 16;
#pragma unroll
    for (int mf = 0; mf < 8; ++mf) {
      int rl = mf * 32 + wm * 16 + li;
      int h = rl >> 7, r = rl & 127;
      int byte = (((r >> 1) * 128) + ((r & 1) * 64) + cb) ^ (((r >> 1) & 7) << 4);
      aOff[mf] = h * 4096 + (byte >> 1);
    }
#pragma unroll
    for (int nf = 0; nf < 4; ++nf) {
      int cl = nf * 64 + wn * 16 + li;
      int h = cl >> 7, c = cl & 127;
      int byte = (((c >> 1) * 128) + ((c & 1) * 64) + cb) ^ (((c >> 1) & 7) << 4);
      bOff[nf] = 8192 + h * 4096 + (byte >> 1);
    }
  }

  f32x4 acc[8][4];
  const f32x4 zf = {0.f, 0.f, 0.f, 0.f};
#pragma unroll
  for (int i = 0; i < 8; ++i)
#pragma unroll
    for (int j = 0; j < 4; ++j) acc[i][j] = zf;

  // ---- prologue: tile0 (B,A) + tile1 (B); vmcnt(2) retires tile0 ----
  stB(0, 0, 0); stB(0, 1, 0); stA(0, 0, 0); stA(0, 1, 0);
  stB(1, 0, 1); stB(1, 1, 1);
  asm volatile("s_waitcnt vmcnt(2)" ::: "memory");
  __builtin_amdgcn_s_barrier();
  MFENCE;

  const int NT = K >> 5;
  bf16x8 bfr[4], af[4];
  for (int k = 0; k < NT; ++k) {
    const int bf = k & 1, bn2 = bf ^ 1;
    const int ka = (k + 1 < NT) ? k + 1 : NT - 1;
    const int kb2 = (k + 2 < NT) ? k + 2 : NT - 1;
    // ---- phase 0: B all + A mf0-3; stage A(k+1) -> other buffer ----
#pragma unroll
    for (int nf = 0; nf < 4; ++nf) bfr[nf] = *(const bf16x8*)&lds[bf][bOff[nf]];
#pragma unroll
    for (int i = 0; i < 4; ++i) af[i] = *(const bf16x8*)&lds[bf][aOff[i]];
    stA(bn2, 0, ka); stA(bn2, 1, ka);
    MFENCE; __builtin_amdgcn_s_barrier(); MFENCE;
    __builtin_amdgcn_s_setprio(1);
#pragma unroll
    for (int mf = 0; mf < 4; ++mf)
#pragma unroll
      for (int nf = 0; nf < 4; ++nf)
        acc[mf][nf] = __builtin_amdgcn_mfma_f32_16x16x32_bf16(af[mf], bfr[nf],
                                                              acc[mf][nf], 0, 0, 0);
    __builtin_amdgcn_s_setprio(0);
    MFENCE; __builtin_amdgcn_s_barrier(); MFENCE;
    // ---- phase 1: A mf4-7; stage B(k+2) -> this buffer's freed B slots ----
#pragma unroll
    for (int i = 0; i < 4; ++i) af[i] = *(const bf16x8*)&lds[bf][aOff[4 + i]];
    stB(bf, 0, kb2); stB(bf, 1, kb2);
    MFENCE; __builtin_amdgcn_s_barrier(); MFENCE;
    __builtin_amdgcn_s_setprio(1);
#pragma unroll
    for (int mf = 0; mf < 4; ++mf)
#pragma unroll
      for (int nf = 0; nf < 4; ++nf)
        acc[4 + mf][nf] = __builtin_amdgcn_mfma_f32_16x16x32_bf16(af[mf], bfr[nf],
                                                                  acc[4 + mf][nf], 0, 0, 0);
    __builtin_amdgcn_s_setprio(0);
    asm volatile("s_waitcnt vmcnt(2)" ::: "memory");  // tile k+1 fully landed
    MFENCE; __builtin_amdgcn_s_barrier(); MFENCE;
  }

  // ---- epilogue ----
  const int orow = (lane >> 4) * 4, ocol = lane & 15;
#pragma unroll
  for (int mf = 0; mf < 8; ++mf) {
    const size_t row0 = trow0 + mf * 32 + wm * 16 + orow;
#pragma unroll
    for (int nf = 0; nf < 4; ++nf) {
      const size_t col = tcol0 + nf * 64 + wn * 16 + ocol;
#pragma unroll
      for (int r = 0; r < 4; ++r)
        Cout[(row0 + r) * (size_t)N + col] = f2bf(acc[mf][nf][r]);
    }
  }
}

// ---------------- GEMM (128^2 m97-style) for proj: fp32 out ---------------
__global__ __launch_bounds__(256)
void gemm_bt(const ushort* __restrict__ A, const ushort* __restrict__ Bm,
             float* __restrict__ Cout, int M, int N, int K) {
  __shared__ ushort lA[2][128 * 32];
  __shared__ ushort lB[2][128 * 32];
  const int tid = threadIdx.x;
  const int wid = tid >> 6, lane = tid & 63;
  const int bx = blockIdx.x, by = blockIdx.y;
  const size_t rowA0 = (size_t)by * 128, colB0 = (size_t)bx * 128;
  const int sr = lane >> 2, sc = (lane & 3) * 8;

  const ushort* Abase = A + rowA0 * K + sc;
  const ushort* Bbase = Bm + colB0 * K + sc;

  auto stage = [&](int buf, int kt) {
    const ushort* Ak = Abase + (size_t)kt * 32;
    const ushort* Bk = Bbase + (size_t)kt * 32;
    for (int i = 0; i < 2; i++) {
      int chunk = wid * 2 + i;
      int row = chunk * 16 + sr;
      gld_lds16(Ak + (size_t)row * K, &lA[buf][chunk * 512]);
      gld_lds16(Bk + (size_t)row * K, &lB[buf][chunk * 512]);
    }
  };

  f32x4 acc[4][4];
  const f32x4 zf = {0.f, 0.f, 0.f, 0.f};
  for (int i = 0; i < 4; i++)
    for (int j = 0; j < 4; j++) acc[i][j] = zf;

  const int wr = (wid >> 1) * 64, wc = (wid & 1) * 64;
  const int lr = lane & 15, lk = (lane >> 4) * 8;

  stage(0, 0);
  __syncthreads();
  const int NT = K / 32;
  int buf = 0;
  for (int kt = 0; kt < NT; kt++) {
    if (kt + 1 < NT) stage(buf ^ 1, kt + 1);
    bf16x8 af[4], bfr[4];
    for (int i = 0; i < 4; i++)
      af[i] = *(const bf16x8*)&lA[buf][(wr + i * 16 + lr) * 32 + lk];
    for (int j = 0; j < 4; j++)
      bfr[j] = *(const bf16x8*)&lB[buf][(wc + j * 16 + lr) * 32 + lk];
    for (int i = 0; i < 4; i++)
      for (int j = 0; j < 4; j++)
        acc[i][j] = __builtin_amdgcn_mfma_f32_16x16x32_bf16(af[i], bfr[j],
                                                            acc[i][j], 0, 0, 0);
    __syncthreads();
    buf ^= 1;
  }
  const int lq = (lane >> 4) * 4;
  for (int i = 0; i < 4; i++)
    for (int j = 0; j < 4; j++)
      for (int r = 0; r < 4; r++) {
        size_t row = rowA0 + wr + i * 16 + lq + r;
        size_t col = colB0 + wc + j * 16 + lr;
        Cout[row * (size_t)N + col] = acc[i][j][r];
      }
}

// ---------------- RoPE + split to (B,H,T,hd), scale Q by 1/sqrt(hd) -------
__global__ __launch_bounds__(256)
void rope_split(const ushort* __restrict__ qkv, const float* __restrict__ cosb,
                const float* __restrict__ sinb, ushort* __restrict__ Qr,
                ushort* __restrict__ Kr, ushort* __restrict__ Vr) {
  const int bt = blockIdx.x;
  const int b = bt >> 11, t = bt & 2047;
  const ushort* base = qkv + (size_t)bt * (3 * C_);
  const int tid = threadIdx.x;
  const float rs = 0.08838834764831845f;  // 1/sqrt(128)
  for (int i = 0; i < 4; i++) {
    int idx = tid + i * 256;  // 0..1023 = (h, pair)
    int h = idx >> 6, p = idx & 63;
    float c = cosb[t * 64 + p], s = sinb[t * 64 + p];
    size_t src = (size_t)h * HD_ + 2 * p;
    size_t dst = (((size_t)(b * H_ + h)) * T_ + t) * HD_ + 2 * p;
    float x1 = bf2f(base[src]), x2 = bf2f(base[src + 1]);
    Qr[dst] = f2bf((x1 * c - x2 * s) * rs);
    Qr[dst + 1] = f2bf((x1 * s + x2 * c) * rs);
    x1 = bf2f(base[C_ + src]); x2 = bf2f(base[C_ + src + 1]);
    Kr[dst] = f2bf(x1 * c - x2 * s);
    Kr[dst + 1] = f2bf(x1 * s + x2 * c);
    Vr[dst] = base[2 * C_ + src];
    Vr[dst + 1] = base[2 * C_ + src + 1];
  }
}

// ---------------- causal flash attention ---------------------------------
__global__ __launch_bounds__(256)
void attn_fwd(const ushort* __restrict__ Qr, const ushort* __restrict__ Kr,
              const ushort* __restrict__ Vr, ushort* __restrict__ Out) {
  __shared__ ushort lK[32][136];
  __shared__ ushort lV[128][40];
  __shared__ ushort lP[4][16][40];
  const int tid = threadIdx.x, wid = tid >> 6, lane = tid & 63;
  const int bh = blockIdx.y;
  const int b = bh >> 4, h = bh & 15;
  const int pr = blockIdx.x;  // 0..15 -> q-tiles {pr, 31-pr}
  const int lr = lane & 15, g = lane >> 4, lk8 = g * 8;
  const f32x4 zf = {0.f, 0.f, 0.f, 0.f};

  const ushort* Kp = Kr + (size_t)bh * T_ * HD_;
  const ushort* Vp = Vr + (size_t)bh * T_ * HD_;

  int rK[2], cK[2], rV[2], cV[2];
  for (int i = 0; i < 2; i++) {
    int chunk = tid + i * 256;
    rK[i] = chunk >> 4; cK[i] = (chunk & 15) * 8;
    rV[i] = chunk & 31; cV[i] = (chunk >> 5) * 8;
  }

  for (int seg = 0; seg < 2; ++seg) {
    const int qt = seg ? (31 - pr) : pr;
    const int qbase = qt * 64 + wid * 16;
    const ushort* Qp = Qr + ((size_t)bh * T_ + qbase) * HD_;

    bf16x8 qf[4];
    for (int dc = 0; dc < 4; dc++)
      qf[dc] = *(const bf16x8*)(Qp + (size_t)lr * HD_ + dc * 32 + lk8);

    f32x4 o[8];
    for (int dt = 0; dt < 8; dt++) o[dt] = zf;
    float m = -1e30f, l = 0.f;

    bf16x8 kreg[2], vreg[2];
    auto load_tile = [&](int kt) {
      for (int i = 0; i < 2; i++) {
        kreg[i] = *(const bf16x8*)(Kp + ((size_t)(kt * 32 + rK[i])) * HD_ + cK[i]);
        vreg[i] = *(const bf16x8*)(Vp + ((size_t)(kt * 32 + rV[i])) * HD_ + cV[i]);
      }
    };

    const int nkt = 2 * qt + 2;
    load_tile(0);
    for (int kt = 0; kt < nkt; kt++) {
      __syncthreads();
      for (int i = 0; i < 2; i++) {
        *(bf16x8*)&lK[rK[i]][cK[i]] = kreg[i];
        for (int j = 0; j < 8; j++) lV[cV[i] + j][rV[i]] = (ushort)vreg[i][j];
      }
      if (kt + 1 < nkt) load_tile(kt + 1);
      __syncthreads();
      if (kt * 32 <= qbase + 15) {
        f32x4 s[2];
        for (int kn = 0; kn < 2; kn++) {
          f32x4 a = zf;
          for (int dc = 0; dc < 4; dc++) {
            bf16x8 kf = *(const bf16x8*)&lK[kn * 16 + lr][dc * 32 + lk8];
            a = __builtin_amdgcn_mfma_f32_16x16x32_bf16(kf, qf[dc], a, 0, 0, 0);
          }
          s[kn] = a;
        }
        const int qg = qbase + lr;
        if (kt * 32 + 31 > qbase) {
          for (int kn = 0; kn < 2; kn++) {
            int k0 = kt * 32 + kn * 16 + g * 4;
            for (int r = 0; r < 4; r++)
              if (k0 + r > qg) s[kn][r] = -1e30f;
          }
        }
        float pm = fmaxf(fmaxf(fmaxf(s[0][0], s[0][1]), fmaxf(s[0][2], s[0][3])),
                         fmaxf(fmaxf(s[1][0], s[1][1]), fmaxf(s[1][2], s[1][3])));
        pm = fmaxf(pm, __shfl_xor(pm, 16, 64));
        pm = fmaxf(pm, __shfl_xor(pm, 32, 64));
        if (!__all(pm - m <= 5.0f)) {
          float mn = fmaxf(m, pm);
          float a = __expf(m - mn);
          for (int dt = 0; dt < 8; dt++)
            for (int r = 0; r < 4; r++) o[dt][r] *= a;
          l *= a;
          m = mn;
        }
        float p[8];
        float rsum = 0.f;
        for (int kn = 0; kn < 2; kn++)
          for (int r = 0; r < 4; r++) {
            float pv = __expf(s[kn][r] - m);
            p[kn * 4 + r] = pv;
            rsum += pv;
          }
        rsum += __shfl_xor(rsum, 16, 64);
        rsum += __shfl_xor(rsum, 32, 64);
        l += rsum;
        for (int kn = 0; kn < 2; kn++) {
          ushort2 w0, w1;
          w0.x = f2bf(p[kn * 4 + 0]); w0.y = f2bf(p[kn * 4 + 1]);
          w1.x = f2bf(p[kn * 4 + 2]); w1.y = f2bf(p[kn * 4 + 3]);
          *(ushort2*)&lP[wid][lr][kn * 16 + g * 4] = w0;
          *(ushort2*)&lP[wid][lr][kn * 16 + g * 4 + 2] = w1;
        }
        bf16x8 pf = *(const bf16x8*)&lP[wid][lr][lk8];
        for (int dt = 0; dt < 8; dt++) {
          bf16x8 vf = *(const bf16x8*)&lV[dt * 16 + lr][lk8];
          o[dt] = __builtin_amdgcn_mfma_f32_16x16x32_bf16(vf, pf, o[dt], 0, 0, 0);
        }
      }
    }
    float inv = 1.0f / l;
    int qg = qbase + lr;
    size_t obase = ((size_t)b * T_ + qg) * C_ + (size_t)h * HD_;
    for (int dt = 0; dt < 8; dt++) {
      ushort4 w;
      w.x = f2bf(o[dt][0] * inv);
      w.y = f2bf(o[dt][1] * inv);
      w.z = f2bf(o[dt][2] * inv);
      w.w = f2bf(o[dt][3] * inv);
      *(ushort4*)&Out[obase + dt * 16 + g * 4] = w;
    }
  }
}

// ---------------- launch --------------------------------------------------
extern "C" void kernel_launch(void* const* d_in, const int* in_sizes, int n_in,
                              void* d_out, int out_size, void* d_ws,
                              size_t ws_size, hipStream_t stream) {
  (void)in_sizes; (void)n_in; (void)out_size; (void)ws_size;
  const float* x = (const float*)d_in[0];
  const float* cosb = (const float*)d_in[1];
  const float* sinb = (const float*)d_in[2];
  const float* w_qkv = (const float*)d_in[3];
  const float* w_proj = (const float*)d_in[4];

  char* ws = (char*)d_ws;
  ushort* wqkvb = (ushort*)(ws);
  ushort* wprojb = (ushort*)(ws + 25165824);
  ushort* xb = (ushort*)(ws + 25165824 + 8388608);
  ushort* qkv = (ushort*)(ws + 25165824 + 8388608 + 16777216);
  ushort* kr = (ushort*)(ws + 25165824 + 8388608 + 16777216 + 50331648);
  ushort* vr = (ushort*)(ws + 25165824 + 8388608 + 16777216 + 50331648 + 16777216);
  ushort* qr = xb;        // alias: xb dead after GEMM1
  ushort* attn_out = qkv; // alias: qkv dead after rope_split

  k_f2bf<<<8192, 256, 0, stream>>>(x, xb, 2097152);
  k_f2bf<<<12288, 256, 0, stream>>>(w_qkv, wqkvb, 3145728);
  k_f2bf<<<4096, 256, 0, stream>>>(w_proj, wprojb, 1048576);

  // qkv = x @ w_qkv^T : M=4096, N=6144, K=2048  (256^2 8-phase template)
  gemm256<<<384, 512, 0, stream>>>(xb, wqkvb, qkv, 4096, 6144, 2048);
  rope_split<<<4096, 256, 0, stream>>>(qkv, cosb, sinb, qr, kr, vr);
  attn_fwd<<<dim3(16, 32), 256, 0, stream>>>(qr, kr, vr, attn_out);
  // out = attn_out @ w_proj^T : M=4096, N=2048, K=2048
  gemm_bt<<<dim3(16, 32), 256, 0, stream>>>(attn_out, wprojb, (float*)d_out,
                                            4096, 2048, 2048);
}